// Round 13
// baseline (922.707 us; speedup 1.0000x reference)
//
#include <hip/hip_runtime.h>
#include <math.h>

#define H 2048
#define V 50257
#define RPB 16                       // logits rows per block (4 waves x 4 rows)
#define NB2 ((V + RPB - 1) / RPB)    // 3142 logits blocks
#define NPART 128                    // fallback partial blocks

// ---- workspace layout (float indices) ----
// [0, 2048)          h_new
// [2048, 54353)      logits (V)
// fused path:
//   [53248, 56390)   per-block max partials (NB2, padded region to 56448)
//   [56448, 59590)   per-block sumexp partials
//   [59648]          finalize counter (int)
// fallback path (small ws): 128-partials at 53248/53376
#define WS_HNEW  0
#define WS_LOGIT 2048
#define WS_PMAX  53248   // fallback only (128 entries)
#define WS_PSUM  53376   // fallback only (128 entries)
#define WS_PMAX2 53248   // fused: NB2 entries (padded to 3200)
#define WS_PSUM2 56448   // fused: NB2 entries (padded to 3200)
#define WS_CNT   59648   // fused: finalize counter (1 int)
#define WS_END   59712

typedef float f4 __attribute__((ext_vector_type(4)));

__device__ __forceinline__ float waveReduceSum(float v) {
  #pragma unroll
  for (int off = 32; off > 0; off >>= 1) v += __shfl_down(v, off, 64);
  return v;
}
__device__ __forceinline__ float waveReduceMax(float v) {
  #pragma unroll
  for (int off = 32; off > 0; off >>= 1) v = fmaxf(v, __shfl_down(v, off, 64));
  return v;
}
__device__ __forceinline__ float sigmoidf(float x) {
  return 1.f / (1.f + expf(-x));
}

// K1: fused GRU step, 2 waves per h-index (side 0: w_ih vs relu(emb[token]);
// side 1: w_hh vs hidden). Combine in smem. Also zeroes the finalize counter
// for K2 (ws is re-poisoned by the harness every iteration; the K1->K2
// dispatch boundary guarantees the zero is visible to all K2 blocks).
__global__ __launch_bounds__(256) void gru_kernel(
    const int* __restrict__ token, const float* __restrict__ hidden,
    const float* __restrict__ emb, const float* __restrict__ w_ih,
    const float* __restrict__ w_hh, const float* __restrict__ b_ih,
    const float* __restrict__ b_hh, float* __restrict__ ws,
    float* __restrict__ out) {
  if (blockIdx.x == 0 && threadIdx.x == 0) *(int*)(ws + WS_CNT) = 0;
  const int wave = threadIdx.x >> 6;
  const int lane = threadIdx.x & 63;
  const int li   = wave >> 1;      // which h-index in this block
  const int side = wave & 1;       // 0: input side  1: hidden side
  const int i = blockIdx.x * 2 + li;
  __shared__ float sums[2][2][3];  // [li][side][r,z,n]

  const f4* v4 = side ? (const f4*)hidden
                      : (const f4*)(emb + (size_t)token[0] * H);
  const float* wmat = side ? w_hh : w_ih;
  const f4* w_r = (const f4*)(wmat + (size_t)i * H);
  const f4* w_z = (const f4*)(wmat + (size_t)(H + i) * H);
  const f4* w_n = (const f4*)(wmat + (size_t)(2 * H + i) * H);

  float sr = 0.f, sz = 0.f, sn = 0.f;
  #pragma unroll
  for (int k = 0; k < 8; ++k) {
    const int idx = k * 64 + lane;
    f4 xv = v4[idx];
    if (!side) {  // wave-uniform: ReLU on embedding vector
      xv.x = fmaxf(xv.x, 0.f); xv.y = fmaxf(xv.y, 0.f);
      xv.z = fmaxf(xv.z, 0.f); xv.w = fmaxf(xv.w, 0.f);
    }
    f4 a;
    a = w_r[idx]; sr += a.x*xv.x + a.y*xv.y + a.z*xv.z + a.w*xv.w;
    a = w_z[idx]; sz += a.x*xv.x + a.y*xv.y + a.z*xv.z + a.w*xv.w;
    a = w_n[idx]; sn += a.x*xv.x + a.y*xv.y + a.z*xv.z + a.w*xv.w;
  }
  sr = waveReduceSum(sr);
  sz = waveReduceSum(sz);
  sn = waveReduceSum(sn);
  if (lane == 0) {
    sums[li][side][0] = sr;
    sums[li][side][1] = sz;
    sums[li][side][2] = sn;
  }
  __syncthreads();
  if (side == 0 && lane == 0) {
    const float s_ir = sums[li][0][0], s_hr = sums[li][1][0];
    const float s_iz = sums[li][0][1], s_hz = sums[li][1][1];
    const float s_in = sums[li][0][2], s_hn = sums[li][1][2];
    const float r = sigmoidf(s_ir + b_ih[i] + s_hr + b_hh[i]);
    const float z = sigmoidf(s_iz + b_ih[H + i] + s_hz + b_hh[H + i]);
    const float n = tanhf(s_in + b_ih[2 * H + i] + r * (s_hn + b_hh[2 * H + i]));
    const float hn = (1.f - z) * n + z * hidden[i];
    ws[WS_HNEW + i] = hn;
    out[V + i] = hn;   // second output: new hidden state
  }
}

// K2: logits + per-block softmax partial + last-block finalize/writeout.
// 4 rows per wave (32 outstanding dwordx4 = 32 KB in flight per wave), 16
// rows/block. Plain (cached) loads: the harness's 1.6 GB workspace poison
// flushes L3 every iteration, so there is no cross-iteration residency to
// protect and NT hints have no upside.
// After writing its partial each block bumps a device-scope counter; the
// block observing count==NB2-1 merges all partials (L2/L3-resident) and
// writes the V log-softmax outputs itself — no 3rd dispatch.
__global__ __launch_bounds__(256, 4) void logits_kernel(
    const float* __restrict__ w_out, const float* __restrict__ b_out,
    float* __restrict__ ws, float* __restrict__ out, int fused) {
  const int wave = threadIdx.x >> 6;
  const int lane = threadIdx.x & 63;
  const int row0 = blockIdx.x * RPB + wave * 4;
  int   r[4];
  int   valid[4];
  #pragma unroll
  for (int j = 0; j < 4; ++j) {
    valid[j] = (row0 + j < V);
    r[j] = valid[j] ? row0 + j : 0;   // clamped: loads always in-bounds
  }

  const f4* h4 = (const f4*)(ws + WS_HNEW);
  f4 hv[8];
  #pragma unroll
  for (int k = 0; k < 8; ++k) hv[k] = h4[k * 64 + lane];

  const f4* wp0 = (const f4*)(w_out + (size_t)r[0] * H);
  const f4* wp1 = (const f4*)(w_out + (size_t)r[1] * H);
  const f4* wp2 = (const f4*)(w_out + (size_t)r[2] * H);
  const f4* wp3 = (const f4*)(w_out + (size_t)r[3] * H);
  float s0 = 0.f, s1 = 0.f, s2 = 0.f, s3 = 0.f;
  #pragma unroll
  for (int k = 0; k < 8; ++k) {
    const int idx = k * 64 + lane;
    f4 a0 = wp0[idx];
    f4 a1 = wp1[idx];
    f4 a2 = wp2[idx];
    f4 a3 = wp3[idx];
    s0 += a0.x*hv[k].x + a0.y*hv[k].y + a0.z*hv[k].z + a0.w*hv[k].w;
    s1 += a1.x*hv[k].x + a1.y*hv[k].y + a1.z*hv[k].z + a1.w*hv[k].w;
    s2 += a2.x*hv[k].x + a2.y*hv[k].y + a2.z*hv[k].z + a2.w*hv[k].w;
    s3 += a3.x*hv[k].x + a3.y*hv[k].y + a3.z*hv[k].z + a3.w*hv[k].w;
  }
  s0 = waveReduceSum(s0);
  s1 = waveReduceSum(s1);
  s2 = waveReduceSum(s2);
  s3 = waveReduceSum(s3);

  __shared__ float lv[RPB];
  if (lane == 0) {
    float sv[4] = {s0, s1, s2, s3};
    #pragma unroll
    for (int j = 0; j < 4; ++j) {
      const float l = sv[j] + b_out[r[j]];
      lv[wave * 4 + j] = valid[j] ? l : -INFINITY;
      if (valid[j]) ws[WS_LOGIT + row0 + j] = l;
    }
  }
  if (!fused) return;
  __syncthreads();

  __shared__ int sLast;
  if (threadIdx.x == 0) {
    float m = -INFINITY;
    #pragma unroll
    for (int j = 0; j < RPB; ++j) m = fmaxf(m, lv[j]);
    float ss = 0.f;
    #pragma unroll
    for (int j = 0; j < RPB; ++j) ss += expf(lv[j] - m);  // exp(-inf)=0
    ws[WS_PMAX2 + blockIdx.x] = m;
    ws[WS_PSUM2 + blockIdx.x] = ss;
    __threadfence();  // release: logits + partial visible device-wide
    const int old = atomicAdd((int*)(ws + WS_CNT), 1);
    sLast = (old == NB2 - 1);
  }
  __syncthreads();
  if (!sLast) return;

  // ---- finalize (one block): merge NB2 partials, write out ----
  __threadfence();  // acquire: see all other blocks' writes
  float m = -INFINITY, ss = 0.f;
  for (int j = threadIdx.x; j < NB2; j += 256) {
    const float pm = ws[WS_PMAX2 + j];
    const float ps = ws[WS_PSUM2 + j];
    const float nm = fmaxf(m, pm);
    ss = ss * expf(m - nm) + ps * expf(pm - nm);
    m = nm;
  }
  #pragma unroll
  for (int off = 32; off > 0; off >>= 1) {
    const float m2 = __shfl_down(m, off, 64);
    const float ss2 = __shfl_down(ss, off, 64);
    const float nm = fmaxf(m, m2);
    ss = ss * expf(m - nm) + ss2 * expf(m2 - nm);
    m = nm;
  }
  __shared__ float redM[4], redS[4];
  __shared__ float sLse;
  if (lane == 0) { redM[wave] = m; redS[wave] = ss; }
  __syncthreads();
  if (threadIdx.x == 0) {
    float M = -INFINITY, S = 0.f;
    #pragma unroll
    for (int w = 0; w < 4; ++w) {
      const float nm = fmaxf(M, redM[w]);
      S = S * expf(M - nm) + redS[w] * expf(redM[w] - nm);
      M = nm;
    }
    sLse = M + logf(S);
  }
  __syncthreads();
  const float lse = sLse;
  // vectorized writeout: V-1 = 4*12564, one scalar tail element
  const int nvec = V / 4;  // 12564
  const f4* lg4 = (const f4*)(ws + WS_LOGIT);
  f4* out4 = (f4*)out;
  for (int j = threadIdx.x; j < nvec; j += 256) {
    f4 l = lg4[j];
    f4 o = {l.x - lse, l.y - lse, l.z - lse, l.w - lse};
    out4[j] = o;
  }
  if (threadIdx.x == 0) out[V - 1] = ws[WS_LOGIT + V - 1] - lse;
}

// ---- fallback path (small workspace): 128-block partials + writeout ----
__global__ __launch_bounds__(256) void partial_kernel(float* __restrict__ ws) {
  __shared__ float sred[4];
  __shared__ float sbmax;
  const int wave = threadIdx.x >> 6;
  const int lane = threadIdx.x & 63;
  float m = -INFINITY;
  for (int i = blockIdx.x * 256 + threadIdx.x; i < V; i += NPART * 256)
    m = fmaxf(m, ws[WS_LOGIT + i]);
  m = waveReduceMax(m);
  if (lane == 0) sred[wave] = m;
  __syncthreads();
  if (threadIdx.x == 0)
    sbmax = fmaxf(fmaxf(sred[0], sred[1]), fmaxf(sred[2], sred[3]));
  __syncthreads();
  const float M = sbmax;
  float s = 0.f;
  for (int i = blockIdx.x * 256 + threadIdx.x; i < V; i += NPART * 256)
    s += expf(ws[WS_LOGIT + i] - M);
  s = waveReduceSum(s);
  __syncthreads();
  if (lane == 0) sred[wave] = s;
  __syncthreads();
  if (threadIdx.x == 0) {
    ws[WS_PMAX + blockIdx.x] = M;
    ws[WS_PSUM + blockIdx.x] = sred[0] + sred[1] + sred[2] + sred[3];
  }
}

__global__ __launch_bounds__(256) void writeout_kernel(
    const float* __restrict__ ws, float* __restrict__ out) {
  __shared__ float pm[NPART], psv[NPART];
  __shared__ float sM[2], sS[2];
  __shared__ float sLse;
  const int tid = threadIdx.x;
  if (tid < NPART) {
    pm[tid]  = ws[WS_PMAX + tid];
    psv[tid] = ws[WS_PSUM + tid];
  }
  __syncthreads();
  if (tid < NPART) {
    float m = waveReduceMax(pm[tid]);
    if ((tid & 63) == 0) sM[tid >> 6] = m;
  }
  __syncthreads();
  const float M = fmaxf(sM[0], sM[1]);
  if (tid < NPART) {
    float e = psv[tid] * expf(pm[tid] - M);
    e = waveReduceSum(e);
    if ((tid & 63) == 0) sS[tid >> 6] = e;
  }
  __syncthreads();
  if (tid == 0) sLse = M + logf(sS[0] + sS[1]);
  __syncthreads();
  const float lse = sLse;
  const int i = blockIdx.x * 256 + tid;
  if (i < V) out[i] = ws[WS_LOGIT + i] - lse;
}

extern "C" void kernel_launch(void* const* d_in, const int* in_sizes, int n_in,
                              void* d_out, int out_size, void* d_ws, size_t ws_size,
                              hipStream_t stream) {
  const int*   token  = (const int*)  d_in[0];
  const float* hidden = (const float*)d_in[1];
  const float* emb    = (const float*)d_in[2];
  const float* w_ih   = (const float*)d_in[3];
  const float* w_hh   = (const float*)d_in[4];
  const float* b_ih   = (const float*)d_in[5];
  const float* b_hh   = (const float*)d_in[6];
  const float* w_out  = (const float*)d_in[7];
  const float* b_out  = (const float*)d_in[8];
  float* out = (float*)d_out;
  float* ws  = (float*)d_ws;

  const int fused = (ws_size >= (size_t)WS_END * sizeof(float));

  gru_kernel<<<H / 2, 256, 0, stream>>>(token, hidden, emb, w_ih, w_hh,
                                        b_ih, b_hh, ws, out);
  logits_kernel<<<NB2, 256, 0, stream>>>(w_out, b_out, ws, out, fused);
  if (!fused) {
    partial_kernel<<<NPART, 256, 0, stream>>>(ws);
    writeout_kernel<<<(V + 255) / 256, 256, 0, stream>>>(ws, out);
  }
}